// Round 4
// baseline (348.113 us; speedup 1.0000x reference)
//
#include <hip/hip_runtime.h>

#define NCLS 80
#define REC  255            // 3*85 floats per (b,cell) record in ytrue
#define NA   3
#define BSZ  16
#define MAXB 32

#define G0 13
#define G1 26
#define G2 52
#define GG0 (G0*G0)
#define GG1 (G1*G1)
#define GG2 (G2*G2)
#define CELLS0 (BSZ*NA*GG0)
#define CELLS1 (BSZ*NA*GG1)
#define CELLS2 (BSZ*NA*GG2)
#define TOTAL  (CELLS0+CELLS1+CELLS2)     // 170352

#define MB ((TOTAL+255)/256)   // 666 cell blocks
#define OB 240                 // obj-correction blocks: 4 waves each -> 960 slots
#define NBLK (MB+OB)           // 906 (<= 1024 co-resident @ 4 blocks/CU)
#define MAGIC 0x5EED5EED

#define SCOPE_A __HIP_MEMORY_SCOPE_AGENT

__device__ const float d_anch[3][3][2] = {
  {{116.f, 90.f}, {156.f, 198.f}, {373.f, 326.f}},
  {{ 30.f, 61.f}, { 62.f,  45.f}, { 59.f, 119.f}},
  {{ 10.f, 13.f}, { 16.f,  30.f}, { 33.f,  23.f}},
};

__device__ inline float sp(float x) {          // softplus, stable
  return fmaxf(x, 0.0f) + log1pf(expf(-fabsf(x)));
}
__device__ inline float sigm(float x) { return 1.0f / (1.0f + expf(-x)); }
__device__ inline float wred(float v) {
  #pragma unroll
  for (int off = 32; off > 0; off >>= 1) v += __shfl_down(v, off, 64);
  return v;
}
__device__ inline float wmax(float v) {
  #pragma unroll
  for (int off = 32; off > 0; off >>= 1) v = fmaxf(v, __shfl_xor(v, off, 64));
  return v;
}

// coherent (agent-scope) helpers for cross-block data inside one kernel
__device__ inline int   ald (const int* p)   { return __hip_atomic_load((int*)p,   __ATOMIC_RELAXED, SCOPE_A); }
__device__ inline float aldf(const float* p) { return __hip_atomic_load((float*)p, __ATOMIC_RELAXED, SCOPE_A); }
__device__ inline void  asti(int* p, int v)     { __hip_atomic_store(p, v, __ATOMIC_RELAXED, SCOPE_A); }
__device__ inline void  astf(float* p, float v) { __hip_atomic_store(p, v, __ATOMIC_RELAXED, SCOPE_A); }

// grp (= l*16+b) of a global cell index; all divisors compile-time constants
__device__ inline int cell_grp(int t) {
  if (t < CELLS0) {
    unsigned r = (unsigned)t / (unsigned)GG0; return (int)(r / 3u);
  } else if (t < CELLS0 + CELLS1) {
    unsigned r = (unsigned)(t - CELLS0) / (unsigned)GG1; return 16 + (int)(r / 3u);
  }
  unsigned r = (unsigned)(t - CELLS0 - CELLS1) / (unsigned)GG2; return 32 + (int)(r / 3u);
}

// ---- phase A helper: one thread per obj word -------------------------------
template<int L>
__device__ inline void gather_one(int idx, const float* __restrict__ yt,
                                  int* __restrict__ cnt, float* __restrict__ boxes,
                                  int* __restrict__ total, int* __restrict__ objlist) {
  constexpr int GG = (L == 0) ? GG0 : (L == 1) ? GG1 : GG2;
  unsigned rest = (unsigned)idx / (unsigned)GG;       // const divisor
  int cell = idx - (int)rest * GG;
  unsigned b = rest / 3u;
  int a = (int)(rest - b * 3u);
  size_t base = ((size_t)((int)b * GG + cell) * 3 + a) * 85;
  float obj = yt[base + 4];
  if (obj > 0.5f) {
    int grp = L * BSZ + (int)b;
    int p = __hip_atomic_fetch_add(&cnt[grp], 1, __ATOMIC_RELAXED, SCOPE_A);
    if (p < MAXB) {
      float* d = boxes + (grp * MAXB + p) * 4;
      astf(d + 0, yt[base]);     astf(d + 1, yt[base + 1]);
      astf(d + 2, yt[base + 2]); astf(d + 3, yt[base + 3]);
    }
    int s = __hip_atomic_fetch_add(total, 1, __ATOMIC_RELAXED, SCOPE_A);
    if (s < 1024) asti(&objlist[s], (grp << 18) | (a << 16) | cell);
  }
}

// ---- phase B helper: conf loss of a non-obj-treated cell -------------------
template<int L>
__device__ inline float conf_cell(int idx, const float* __restrict__ fp,
                                  const float4* __restrict__ sbox,
                                  const int* __restrict__ scnt, int gmin) {
  constexpr int GG = (L == 0) ? GG0 : (L == 1) ? GG1 : GG2;
  constexpr int G  = (L == 0) ? G0  : (L == 1) ? G1  : G2;
  unsigned rest = (unsigned)idx / (unsigned)GG;
  int cell = idx - (int)rest * GG;
  unsigned b = rest / 3u;
  int a = (int)(rest - b * 3u);
  int fbase = ((int)(b * 3u) + a) * 85 * GG + cell;
  float t0 = fp[fbase];
  float t1 = fp[fbase + GG];
  float t2 = fp[fbase + 2 * GG];
  float t3 = fp[fbase + 3 * GG];
  float t4 = fp[fbase + 4 * GG];
  unsigned yi = (unsigned)cell / (unsigned)G;
  int xi = cell - (int)yi * G;
  float inv_g = 1.0f / (float)G;
  float aw = d_anch[L][a][0], ah = d_anch[L][a][1];
  float px = (sigm(t0) + (float)xi) * inv_g;
  float py = (sigm(t1) + (float)yi) * inv_g;
  float pw = expf(t2) * aw * (1.0f / 416.0f);
  float ph = expf(t3) * ah * (1.0f / 416.0f);
  int si = L * BSZ + (int)b - gmin;
  int nb = scnt[si]; nb = nb > MAXB ? MAXB : nb;
  const float4* bx = sbox + si * MAXB;
  float pminx = px - pw * 0.5f, pmaxx = px + pw * 0.5f;
  float pminy = py - ph * 0.5f, pmaxy = py + ph * 0.5f;
  float pa = pw * ph;
  float best = 0.0f;
  for (int j = 0; j < nb; ++j) {
    float4 tb = bx[j];
    float iw = fminf(pmaxx, tb.x + tb.z * 0.5f) - fmaxf(pminx, tb.x - tb.z * 0.5f);
    float ih = fminf(pmaxy, tb.y + tb.w * 0.5f) - fmaxf(pminy, tb.y - tb.w * 0.5f);
    iw = fmaxf(iw, 0.f); ih = fmaxf(ih, 0.f);
    float inter = iw * ih;
    best = fmaxf(best, inter / (pa + tb.z * tb.w - inter));
  }
  return sp(t4) * (best < 0.5f ? 1.0f : 0.0f);   // obj treated as 0 here
}

// ---- the single fused kernel ----------------------------------------------
__global__ __launch_bounds__(256, 4)
void fused_kernel(const float* __restrict__ f0, const float* __restrict__ f1,
                  const float* __restrict__ f2, const float* __restrict__ y0,
                  const float* __restrict__ y1, const float* __restrict__ y2,
                  float* __restrict__ acc, int* __restrict__ cnt,
                  int* __restrict__ total, int* __restrict__ done,
                  int* __restrict__ flag, int* __restrict__ arrive,
                  int* __restrict__ objlist, float* __restrict__ boxes,
                  float* __restrict__ out) {
  const int bid = blockIdx.x;
  const int tid = threadIdx.x;
  const int lane = tid & 63, wv = tid >> 6;

  // ---- init (block 0) / wait for init (everyone else) ----------------------
  if (tid == 0) {
    if (bid == 0) {
      #pragma unroll
      for (int i = 0; i < 4; ++i) astf(&acc[i], 0.0f);
      for (int i = 0; i < 48; ++i) asti(&cnt[i], 0);
      asti(total, 0); asti(done, 0); asti(arrive, 0);
      __hip_atomic_store(flag, MAGIC, __ATOMIC_RELEASE, SCOPE_A);
    } else {
      while (__hip_atomic_load(flag, __ATOMIC_ACQUIRE, SCOPE_A) != MAGIC)
        __builtin_amdgcn_s_sleep(4);
    }
  }
  __syncthreads();

  // ---- phase A: gather obj boxes (all blocks participate) ------------------
  {
    int t = bid * 256 + tid;
    if (t < TOTAL) {
      if (t < CELLS0)               gather_one<0>(t,                   y0, cnt, boxes, total, objlist);
      else if (t < CELLS0 + CELLS1) gather_one<1>(t - CELLS0,          y1, cnt, boxes, total, objlist);
      else                          gather_one<2>(t - CELLS0 - CELLS1, y2, cnt, boxes, total, objlist);
    }
  }
  __syncthreads();

  // ---- device-wide barrier --------------------------------------------------
  if (tid == 0) {
    __hip_atomic_fetch_add(arrive, 1, __ATOMIC_ACQ_REL, SCOPE_A);
    while (__hip_atomic_load(arrive, __ATOMIC_ACQUIRE, SCOPE_A) < NBLK)
      __builtin_amdgcn_s_sleep(4);
  }
  __syncthreads();

  // ---- phase B: losses ------------------------------------------------------
  __shared__ float4 sbox[2 * MAXB];
  __shared__ int scnt[2];
  float vxy = 0.f, vwh = 0.f, vconf = 0.f, vcls = 0.f;

  if (bid < MB) {
    int tfirst = bid * 256;
    int tlast  = min(tfirst + 255, TOTAL - 1);
    int gmin = cell_grp(tfirst);
    int ng = cell_grp(tlast) - gmin + 1;               // <= 2 (group span >= 507 cells)
    if (tid < ng * MAXB) {
      const float* s = boxes + (gmin * MAXB + tid) * 4;
      float4 v;
      v.x = aldf(s); v.y = aldf(s + 1); v.z = aldf(s + 2); v.w = aldf(s + 3);
      sbox[tid] = v;
    }
    if (tid < ng) scnt[tid] = ald(&cnt[gmin + tid]);
    __syncthreads();
    int t = tfirst + tid;
    if (t < TOTAL) {
      if (t < CELLS0)                vconf = conf_cell<0>(t,                   f0, sbox, scnt, gmin);
      else if (t < CELLS0 + CELLS1)  vconf = conf_cell<1>(t - CELLS0,          f1, sbox, scnt, gmin);
      else                           vconf = conf_cell<2>(t - CELLS0 - CELLS1, f2, sbox, scnt, gmin);
    }
  } else {
    // obj-correction path: one wave per obj cell (e is wave-uniform)
    int e = (bid - MB) * 4 + wv;
    int tot = ald(total); if (tot > 1024) tot = 1024;
    if (e < tot) {
      int pk = ald(&objlist[e]);
      int grp = pk >> 18, a = (pk >> 16) & 3, cell = pk & 0xFFFF;
      int l = grp >> 4, b = grp & 15;
      int GGv, Gv;
      const float *fp, *yp;
      if (l == 0)      { GGv = GG0; Gv = G0; fp = f0; yp = y0; }
      else if (l == 1) { GGv = GG1; Gv = G1; fp = f1; yp = y1; }
      else             { GGv = GG2; Gv = G2; fp = f2; yp = y2; }
      int rec   = b * GGv + cell;
      int ybase = rec * REC + a * 85;
      int fbase = (b * NA + a) * 85 * GGv + cell;
      float objv = yp[ybase + 4];                      // broadcast load (==1.0)

      // lane-parallel class BCE: lane c covers class c, lanes 0..15 also c+64
      float lg = fp[fbase + (5 + lane) * GGv];
      vcls = sp(lg) - lg * yp[ybase + 5 + lane];
      if (lane < 16) {
        int c2 = lane + 64;
        float lg2 = fp[fbase + (5 + c2) * GGv];
        vcls += sp(lg2) - lg2 * yp[ybase + 5 + c2];
      }
      vcls *= objv;

      // all lanes: broadcast feats scalars, redundant box math
      float t0 = fp[fbase];
      float t1 = fp[fbase + GGv];
      float t2 = fp[fbase + 2 * GGv];
      float t3 = fp[fbase + 3 * GGv];
      float t4 = fp[fbase + 4 * GGv];
      int yi = (l == 0) ? cell / G0 : (l == 1) ? cell / G1 : cell / G2;
      int xi = cell - yi * Gv;
      float aw = d_anch[l][a][0], ah = d_anch[l][a][1];
      float px = (sigm(t0) + (float)xi) / (float)Gv;
      float py = (sigm(t1) + (float)yi) / (float)Gv;
      float pw = expf(t2) * aw * (1.0f / 416.0f);
      float ph = expf(t3) * ah * (1.0f / 416.0f);
      int nb = ald(&cnt[grp]); nb = nb > MAXB ? MAXB : nb;
      float iou = 0.0f;
      if (lane < nb) {                                  // lane-parallel IoU
        const float* s = boxes + (grp * MAXB + lane) * 4;
        float bx = aldf(s), by = aldf(s + 1), bz = aldf(s + 2), bw = aldf(s + 3);
        float iw = fminf(px + pw * 0.5f, bx + bz * 0.5f) - fmaxf(px - pw * 0.5f, bx - bz * 0.5f);
        float ih = fminf(py + ph * 0.5f, by + bw * 0.5f) - fmaxf(py - ph * 0.5f, by - bw * 0.5f);
        iw = fmaxf(iw, 0.f); ih = fmaxf(ih, 0.f);
        float inter = iw * ih;
        iou = inter / (pw * ph + bz * bw - inter);
      }
      float best = wmax(iou);
      if (lane == 0) {
        float ytx = yp[ybase], yty = yp[ybase + 1];
        float ytw = yp[ybase + 2], yth = yp[ybase + 3];
        float rtx = ytx * (float)Gv - (float)xi;
        float rty = yty * (float)Gv - (float)yi;
        float scale = 2.0f - ytw * yth;
        vxy = objv * scale * ((sp(t0) - t0 * rtx) + (sp(t1) - t1 * rty));
        float rtw = logf(ytw * 416.0f / aw);
        float rth = logf(yth * 416.0f / ah);
        vwh = objv * scale * ((t2 - rtw) * (t2 - rtw) + (t3 - rth) * (t3 - rth));
        // main pass added sp(t4)*ignore (obj=0 form); replace with true term
        float ign = best < 0.5f ? 1.0f : 0.0f;
        float spt4 = sp(t4);
        float bce4 = spt4 - t4 * objv;
        vconf = bce4 * (objv + (1.0f - objv) * ign) - spt4 * ign;
      }
    }
  }

  // ---- block reduction: wave shuffle -> LDS -> 4 atomics per block ---------
  __shared__ float sm[4][4];
  vxy = wred(vxy); vwh = wred(vwh); vconf = wred(vconf); vcls = wred(vcls);
  if (lane == 0) { sm[0][wv] = vxy; sm[1][wv] = vwh; sm[2][wv] = vconf; sm[3][wv] = vcls; }
  __syncthreads();
  if (tid < 4) {
    float s = sm[tid][0] + sm[tid][1] + sm[tid][2] + sm[tid][3];
    atomicAdd(&acc[tid], s);
  }
  __syncthreads();

  // ---- last finishing block writes the outputs -----------------------------
  if (tid == 0) {
    __threadfence();
    int d = __hip_atomic_fetch_add(done, 1, __ATOMIC_ACQ_REL, SCOPE_A);
    if (d == NBLK - 1) {
      float xy = atomicAdd(&acc[0], 0.0f) * (1.0f / BSZ);
      float wh = atomicAdd(&acc[1], 0.0f) * (1.0f / BSZ);
      float cf = atomicAdd(&acc[2], 0.0f) * (1.0f / BSZ);
      float cl = atomicAdd(&acc[3], 0.0f) * (1.0f / BSZ);
      out[0] = xy + wh + cf + cl;
      out[1] = xy; out[2] = wh; out[3] = cf; out[4] = cl;
    }
  }
}

extern "C" void kernel_launch(void* const* d_in, const int* in_sizes, int n_in,
                              void* d_out, int out_size, void* d_ws, size_t ws_size,
                              hipStream_t stream) {
  // setup_inputs() dict order: feats0, ytrue0, feats1, ytrue1, feats2, ytrue2
  const float* f0 = (const float*)d_in[0];
  const float* y0 = (const float*)d_in[1];
  const float* f1 = (const float*)d_in[2];
  const float* y1 = (const float*)d_in[3];
  const float* f2 = (const float*)d_in[4];
  const float* y2 = (const float*)d_in[5];

  float* acc     = (float*)d_ws;                       // 4 floats @ 0
  int*   cnt     = (int*)((char*)d_ws + 64);           // 48 ints
  int*   total   = (int*)((char*)d_ws + 256);          // 1 int
  int*   done    = (int*)((char*)d_ws + 260);          // 1 int
  int*   flag    = (int*)((char*)d_ws + 264);          // 1 int (init-done magic)
  int*   arrive  = (int*)((char*)d_ws + 268);          // 1 int (grid barrier)
  int*   objlist = (int*)((char*)d_ws + 512);          // 1024 ints
  float* boxes   = (float*)((char*)d_ws + 8192);       // 48*32*4 floats

  fused_kernel<<<NBLK, 256, 0, stream>>>(f0, f1, f2, y0, y1, y2,
                                         acc, cnt, total, done, flag, arrive,
                                         objlist, boxes, (float*)d_out);
}

// Round 5
// 166.755 us; speedup vs baseline: 2.0876x; 2.0876x over previous
//
#include <hip/hip_runtime.h>

#define NCLS 80
#define REC  255            // 3*85 floats per (b,cell) record in ytrue
#define NA   3
#define BSZ  16
#define MAXB 32

#define G0 13
#define G1 26
#define G2 52
#define GG0 (G0*G0)
#define GG1 (G1*G1)
#define GG2 (G2*G2)
#define CELLS0 (BSZ*NA*GG0)
#define CELLS1 (BSZ*NA*GG1)
#define CELLS2 (BSZ*NA*GG2)
#define TOTAL  (CELLS0+CELLS1+CELLS2)     // 170352

#define R0 (BSZ*GG0)
#define R1 (BSZ*GG1)
#define R2 (BSZ*GG2)
#define F0 (R0*REC/4)       // float4 count per layer ytrue (all divisible by 4)
#define F1 (R1*REC/4)
#define F2 (R2*REC/4)
#define FT (F0+F1+F2)

#define MB ((TOTAL+255)/256)   // 666 main blocks
#define OB 240                 // obj-correction blocks: 4 waves each -> 960 slots

__device__ const float d_anch[3][3][2] = {
  {{116.f, 90.f}, {156.f, 198.f}, {373.f, 326.f}},
  {{ 30.f, 61.f}, { 62.f,  45.f}, { 59.f, 119.f}},
  {{ 10.f, 13.f}, { 16.f,  30.f}, { 33.f,  23.f}},
};

__device__ inline float sp(float x) {          // softplus, stable
  return fmaxf(x, 0.0f) + log1pf(expf(-fabsf(x)));
}
__device__ inline float sigm(float x) { return 1.0f / (1.0f + expf(-x)); }
__device__ inline float wred(float v) {
  #pragma unroll
  for (int off = 32; off > 0; off >>= 1) v += __shfl_down(v, off, 64);
  return v;
}

// ---------------- kernel 1: coalesced ytrue scan -> boxes + obj list --------
template<int L>
__device__ inline void scan4(int q, const float* __restrict__ yt,
                             int* __restrict__ cnt, float* __restrict__ boxes,
                             int* __restrict__ total, int* __restrict__ objlist) {
  constexpr int GG = (L == 0) ? GG0 : (L == 1) ? GG1 : GG2;
  float4 v = ((const float4*)yt)[q];
  float vv[4] = {v.x, v.y, v.z, v.w};
  int w0 = q * 4;
  #pragma unroll
  for (int k = 0; k < 4; ++k) {
    int w = w0 + k;
    unsigned rec = (unsigned)w / 255u;          // const divisor -> magic mul
    int o = w - (int)rec * 255;
    if (o == 4 || o == 89 || o == 174) {
      float obj = vv[k];
      if (obj > 0.5f) {
        int a = (o == 89) ? 1 : (o == 174) ? 2 : 0;
        unsigned b = rec / (unsigned)GG;        // const divisor
        int cell = (int)(rec - b * (unsigned)GG);
        int grp = L * BSZ + (int)b;
        int p = atomicAdd(&cnt[grp], 1);
        if (p < MAXB) {
          const float* rb = yt + (size_t)rec * REC + a * 85;
          float* d = boxes + (grp * MAXB + p) * 4;
          d[0] = rb[0]; d[1] = rb[1]; d[2] = rb[2]; d[3] = rb[3];
        }
        int s = atomicAdd(total, 1);
        if (s < 1024) objlist[s] = (grp << 18) | (a << 16) | cell;
      }
    }
  }
}

__global__ __launch_bounds__(256)
void scan_kernel(const float* __restrict__ y0, const float* __restrict__ y1,
                 const float* __restrict__ y2, int* __restrict__ cnt,
                 float* __restrict__ boxes, int* __restrict__ total,
                 int* __restrict__ objlist) {
  int nth = gridDim.x * blockDim.x;
  for (int q = blockIdx.x * blockDim.x + threadIdx.x; q < FT; q += nth) {
    if (q < F0)           scan4<0>(q,           y0, cnt, boxes, total, objlist);
    else if (q < F0 + F1) scan4<1>(q - F0,      y1, cnt, boxes, total, objlist);
    else                  scan4<2>(q - F0 - F1, y2, cnt, boxes, total, objlist);
  }
}

// ---------------- kernel 2: losses (main conf + obj corrections + finalize) -
__device__ inline float best_iou(float px, float py, float pw, float ph,
                                 const float* __restrict__ boxes, int grp, int nb) {
  float pminx = px - pw * 0.5f, pmaxx = px + pw * 0.5f;
  float pminy = py - ph * 0.5f, pmaxy = py + ph * 0.5f;
  float pa = pw * ph;
  const float4* bxs = (const float4*)(boxes + grp * MAXB * 4);
  float best = 0.0f;
  for (int j = 0; j < nb; ++j) {
    float4 tb = bxs[j];
    float iw = fminf(pmaxx, tb.x + tb.z * 0.5f) - fmaxf(pminx, tb.x - tb.z * 0.5f);
    float ih = fminf(pmaxy, tb.y + tb.w * 0.5f) - fmaxf(pminy, tb.y - tb.w * 0.5f);
    iw = fmaxf(iw, 0.f); ih = fmaxf(ih, 0.f);
    float inter = iw * ih;
    best = fmaxf(best, inter / (pa + tb.z * tb.w - inter));
  }
  return best;
}

template<int L>
__device__ inline float conf_cell(int idx, const float* __restrict__ fp,
                                  const int* __restrict__ cnt,
                                  const float* __restrict__ boxes) {
  constexpr int GG = (L == 0) ? GG0 : (L == 1) ? GG1 : GG2;
  constexpr int G  = (L == 0) ? G0  : (L == 1) ? G1  : G2;
  unsigned rest = (unsigned)idx / (unsigned)GG;       // const divisors
  int cell = idx - (int)rest * GG;
  unsigned b = rest / 3u;
  int a = (int)(rest - b * 3u);
  int fbase = ((int)(b * 3u) + a) * 85 * GG + cell;
  float t0 = fp[fbase];
  float t1 = fp[fbase + GG];
  float t2 = fp[fbase + 2 * GG];
  float t3 = fp[fbase + 3 * GG];
  float t4 = fp[fbase + 4 * GG];
  unsigned yi = (unsigned)cell / (unsigned)G;
  int xi = cell - (int)yi * G;
  float inv_g = 1.0f / (float)G;
  float aw = d_anch[L][a][0], ah = d_anch[L][a][1];
  float px = (sigm(t0) + (float)xi) * inv_g;
  float py = (sigm(t1) + (float)yi) * inv_g;
  float pw = expf(t2) * aw * (1.0f / 416.0f);
  float ph = expf(t3) * ah * (1.0f / 416.0f);
  int grp = L * BSZ + (int)b;
  int nb = cnt[grp]; nb = nb > MAXB ? MAXB : nb;
  float best = best_iou(px, py, pw, ph, boxes, grp, nb);
  return sp(t4) * (best < 0.5f ? 1.0f : 0.0f);        // obj treated as 0 here
}

__global__ __launch_bounds__(256)
void loss_kernel(const float* __restrict__ f0, const float* __restrict__ f1,
                 const float* __restrict__ f2, const float* __restrict__ y0,
                 const float* __restrict__ y1, const float* __restrict__ y2,
                 const int* __restrict__ cnt, const float* __restrict__ boxes,
                 const int* __restrict__ total, const int* __restrict__ objlist,
                 float* __restrict__ acc, int* __restrict__ done,
                 float* __restrict__ out) {
  float vxy = 0.f, vwh = 0.f, vconf = 0.f, vcls = 0.f;
  int lane = threadIdx.x & 63, wv = threadIdx.x >> 6;

  if (blockIdx.x < MB) {
    int t = blockIdx.x * 256 + threadIdx.x;
    if (t < TOTAL) {
      if (t < CELLS0)                vconf = conf_cell<0>(t,                  f0, cnt, boxes);
      else if (t < CELLS0 + CELLS1)  vconf = conf_cell<1>(t - CELLS0,         f1, cnt, boxes);
      else                           vconf = conf_cell<2>(t - CELLS0 - CELLS1, f2, cnt, boxes);
    }
  } else {
    // obj-correction path: one wave per obj cell
    int e = (blockIdx.x - MB) * 4 + wv;
    int tot = *total; if (tot > 1024) tot = 1024;
    if (e < tot) {
      int pk = objlist[e];
      int grp = pk >> 18, a = (pk >> 16) & 3, cell = pk & 0xFFFF;
      int l = grp >> 4, b = grp & 15;
      int GGv, Gv;
      const float *fp, *yp;
      if (l == 0)      { GGv = GG0; Gv = G0; fp = f0; yp = y0; }
      else if (l == 1) { GGv = GG1; Gv = G1; fp = f1; yp = y1; }
      else             { GGv = GG2; Gv = G2; fp = f2; yp = y2; }
      int rec   = b * GGv + cell;
      int ybase = rec * REC + a * 85;
      int fbase = (b * NA + a) * 85 * GGv + cell;
      float objv = yp[ybase + 4];               // broadcast load (==1.0)

      // lane-parallel class BCE: lane c covers class c, lanes 0..15 also c+64
      {
        float lg = fp[fbase + (5 + lane) * GGv];
        vcls = sp(lg) - lg * yp[ybase + 5 + lane];
        if (lane < 16) {
          int c2 = lane + 64;
          float lg2 = fp[fbase + (5 + c2) * GGv];
          vcls += sp(lg2) - lg2 * yp[ybase + 5 + c2];
        }
        vcls *= objv;
      }

      if (lane == 0) {
        float t0 = fp[fbase];
        float t1 = fp[fbase + GGv];
        float t2 = fp[fbase + 2 * GGv];
        float t3 = fp[fbase + 3 * GGv];
        float t4 = fp[fbase + 4 * GGv];
        float ytx = yp[ybase], yty = yp[ybase + 1];
        float ytw = yp[ybase + 2], yth = yp[ybase + 3];
        int yi = cell / Gv, xi = cell - yi * Gv;
        float aw = d_anch[l][a][0], ah = d_anch[l][a][1];
        float rtx = ytx * (float)Gv - (float)xi;
        float rty = yty * (float)Gv - (float)yi;
        float scale = 2.0f - ytw * yth;
        vxy = objv * scale * ((sp(t0) - t0 * rtx) + (sp(t1) - t1 * rty));
        float rtw = logf(ytw * 416.0f / aw);
        float rth = logf(yth * 416.0f / ah);
        vwh = objv * scale * ((t2 - rtw) * (t2 - rtw) + (t3 - rth) * (t3 - rth));
        // conf correction: main pass added sp(t4)*ignore (obj=0 form);
        // true contribution is (sp(t4)-t4*obj)*(obj+(1-obj)*ignore)
        float px = (sigm(t0) + (float)xi) / (float)Gv;
        float py = (sigm(t1) + (float)yi) / (float)Gv;
        float pw = expf(t2) * aw * (1.0f / 416.0f);
        float ph = expf(t3) * ah * (1.0f / 416.0f);
        int nb = cnt[grp]; nb = nb > MAXB ? MAXB : nb;
        float best = best_iou(px, py, pw, ph, boxes, grp, nb);
        float ign = best < 0.5f ? 1.0f : 0.0f;
        float spt4 = sp(t4);
        float bce4 = spt4 - t4 * objv;
        vconf = bce4 * (objv + (1.0f - objv) * ign) - spt4 * ign;
      }
    }
  }

  // block reduction: wave shuffle -> LDS -> 4 atomics per block
  __shared__ float sm[4][4];
  vxy = wred(vxy); vwh = wred(vwh); vconf = wred(vconf); vcls = wred(vcls);
  if (lane == 0) { sm[0][wv] = vxy; sm[1][wv] = vwh; sm[2][wv] = vconf; sm[3][wv] = vcls; }
  __syncthreads();
  if (threadIdx.x < 4) {
    float s = sm[threadIdx.x][0] + sm[threadIdx.x][1] + sm[threadIdx.x][2] + sm[threadIdx.x][3];
    atomicAdd(&acc[threadIdx.x], s);
  }
  __syncthreads();

  // last block finalizes
  if (threadIdx.x == 0) {
    __threadfence();
    int d = atomicAdd(done, 1);
    if (d == (int)gridDim.x - 1) {
      float xy = atomicAdd(&acc[0], 0.0f) * (1.0f / BSZ);
      float wh = atomicAdd(&acc[1], 0.0f) * (1.0f / BSZ);
      float cf = atomicAdd(&acc[2], 0.0f) * (1.0f / BSZ);
      float cl = atomicAdd(&acc[3], 0.0f) * (1.0f / BSZ);
      out[0] = xy + wh + cf + cl;
      out[1] = xy; out[2] = wh; out[3] = cf; out[4] = cl;
    }
  }
}

extern "C" void kernel_launch(void* const* d_in, const int* in_sizes, int n_in,
                              void* d_out, int out_size, void* d_ws, size_t ws_size,
                              hipStream_t stream) {
  // setup_inputs() dict order: feats0, ytrue0, feats1, ytrue1, feats2, ytrue2
  const float* f0 = (const float*)d_in[0];
  const float* y0 = (const float*)d_in[1];
  const float* f1 = (const float*)d_in[2];
  const float* y1 = (const float*)d_in[3];
  const float* f2 = (const float*)d_in[4];
  const float* y2 = (const float*)d_in[5];

  float* acc     = (float*)d_ws;                       // 4 floats @ 0
  int*   cnt     = (int*)((char*)d_ws + 64);           // 48 ints
  int*   total   = (int*)((char*)d_ws + 256);          // 1 int
  int*   done    = (int*)((char*)d_ws + 260);          // 1 int
  int*   objlist = (int*)((char*)d_ws + 512);          // 1024 ints
  float* boxes   = (float*)((char*)d_ws + 8192);       // 48*32*4 floats

  hipMemsetAsync(d_ws, 0, 512, stream);                // acc+cnt+total+done

  scan_kernel<<<2048, 256, 0, stream>>>(y0, y1, y2, cnt, boxes, total, objlist);
  loss_kernel<<<MB + OB, 256, 0, stream>>>(f0, f1, f2, y0, y1, y2,
                                           cnt, boxes, total, objlist,
                                           acc, done, (float*)d_out);
}